// Round 8
// baseline (173.787 us; speedup 1.0000x reference)
//
#include <hip/hip_runtime.h>
#include <hip/hip_bf16.h>

#define N_Q 50000
#define H_NB 32
#define K_KP 15
#define C_CH 128
#define KP_EXT 1.2f

typedef __attribute__((ext_vector_type(8))) short bf16x8;   // MFMA A/B operand
typedef __attribute__((ext_vector_type(4))) float f32x4;    // MFMA C/D

static __device__ __forceinline__ short f2bf(float f) {
    __hip_bfloat16 h = __float2bfloat16(f);   // RNE
    return *reinterpret_cast<short*>(&h);
}

// prepass: (a) x f32 [N,C] -> bf16 with channel permutation c' = (c&15)*8+(c>>4)
// so lane ln's 8 needed channels (c = t*16+ln) are contiguous 16B;
// (b) s_pts [M,3] -> padded float4 rows (one dwordx4 per neighbor gather).
__global__ __launch_bounds__(256)
void cvt_perm_kernel(const float* __restrict__ x, const float* __restrict__ s_pts,
                     ushort* __restrict__ xb, float4* __restrict__ sp4) {
    const int t  = threadIdx.x;
    const int m  = blockIdx.x * 16 + (t >> 4);   // 3125*16 = 50000 exact
    const int ln = t & 15;
    const float* xr = x + (size_t)m * C_CH;
    uint v[8];
#pragma unroll
    for (int i = 0; i < 8; ++i)
        v[i] = (uint)(ushort)f2bf(xr[ln + 16 * i]);
    uint4 o;
    o.x = v[0] | (v[1] << 16);
    o.y = v[2] | (v[3] << 16);
    o.z = v[4] | (v[5] << 16);
    o.w = v[6] | (v[7] << 16);
    *(uint4*)(xb + (size_t)m * C_CH + ln * 8) = o;
    if (ln == 0) {
        sp4[m] = make_float4(s_pts[3*m], s_pts[3*m+1], s_pts[3*m+2], 0.f);
    }
}

// One wave per point, register-only (no LDS). P[k,c] = sum_h w[h,k]*x[h,c]
// via 8x mfma_f32_16x16x32_bf16. A (w) computed per-lane in the exact
// fragment layout; B gathered as ONE dwordx4 per row from permuted xb and
// redistributed to tile fragments with compile-time v_perm_b32.
__global__ __launch_bounds__(256, 8)
void kpconv_mfma4(const float* __restrict__ q_pts,
                  const float4* __restrict__ sp4,
                  const int*   __restrict__ inds,
                  const ushort* __restrict__ xb,
                  const float* __restrict__ kp,
                  const float* __restrict__ dw,
                  const float* __restrict__ bias,
                  float*       __restrict__ out)
{
    const int wave = threadIdx.x >> 6;
    const int l    = threadIdx.x & 63;
    const int n    = blockIdx.x * 4 + wave;     // 12500*4 = 50000 exact
    const int lg   = l >> 4;                    // h-block 0..3
    const int ln   = l & 15;                    // k (A) / col (B,C)

    const int4* ip = (const int4*)(inds + n * H_NB + lg * 8);
    const int4 i0 = ip[0], i1 = ip[1];
    const int idxv[8] = {i0.x,i0.y,i0.z,i0.w,i1.x,i1.y,i1.z,i1.w};

    // ---- 8 fat gathers: 16B of permuted bf16 row per lane. Every MFMA tile
    // consumes ALL of rv[0..7], so all 8 stay in flight together. ----
    uint4 rv[8];
#pragma unroll
    for (int j = 0; j < 8; ++j)
        rv[j] = *(const uint4*)(xb + (size_t)(unsigned)idxv[j] * C_CH + ln * 8);

    // ---- A fragment (w) while gathers are in flight ----
    const float qx = q_pts[n*3+0], qy = q_pts[n*3+1], qz = q_pts[n*3+2];
    const int kkc = ln < K_KP ? ln : (K_KP - 1);
    // fold q + kp into one offset: d = || s - (q + kp) ||
    const float ox = qx + kp[kkc*3+0];
    const float oy = qy + kp[kkc*3+1];
    const float oz = qz + kp[kkc*3+2];

    bf16x8 afrag;
#pragma unroll
    for (int j = 0; j < 8; ++j) {
        const float4 p = sp4[(unsigned)idxv[j]];   // one dwordx4 per neighbor
        const float dx = p.x - ox, dy = p.y - oy, dz = p.z - oz;
        const float d  = sqrtf(fmaf(dx, dx, fmaf(dy, dy, dz*dz)));
        float w = fmaxf(1.0f - d * (1.0f/KP_EXT), 0.0f);
        if (ln == 15) w = 0.0f;                 // pad kernel-point row
        afrag[j] = f2bf(w);
    }

    f32x4 acc[8];
#pragma unroll
    for (int t = 0; t < 8; ++t) acc[t] = (f32x4){0.f, 0.f, 0.f, 0.f};

    const uint* rw = (const uint*)&rv[0];       // rv as uint[32]; indices below
                                                // are compile-time constants
#pragma unroll
    for (int t = 0; t < 8; ++t) {
        const uint sel = (t & 1) ? 0x07060302u : 0x05040100u;  // halfword t&1
        const int  w   = t >> 1;                               // word in uint4
        union { bf16x8 v; uint u[4]; } bf;
#pragma unroll
        for (int r = 0; r < 4; ++r) {
            bf.u[r] = __builtin_amdgcn_perm(rw[(2*r+1)*4 + w], rw[(2*r)*4 + w], sel);
        }
        acc[t] = __builtin_amdgcn_mfma_f32_16x16x32_bf16(afrag, bf.v, acc[t], 0, 0, 0);
    }

    // ---- epilogue: out[c] = sum_k dw[k,c]*P[k,c] + bias[c] ----
    const int rowbase = lg * 4;
#pragma unroll
    for (int t = 0; t < 8; ++t) {
        const int c = t*16 + ln;
        float s = 0.f;
#pragma unroll
        for (int r = 0; r < 4; ++r) {
            const int row = rowbase + r;
            const float dwv = (row < K_KP) ? dw[row * C_CH + c] : 0.f;
            s = fmaf(dwv, acc[t][r], s);
        }
        s += __shfl_xor(s, 16);                 // reduce the 4 row-groups
        s += __shfl_xor(s, 32);
        s += bias[c];
        if (l < 16) out[n * C_CH + c] = s;
    }
}

// fallback (ws too small): R5's fp32-gather kernel, known-good at 117us
__global__ __launch_bounds__(256, 4)
void kpconv_mfma_fb(const float* __restrict__ q_pts,
                    const float* __restrict__ s_pts,
                    const int*   __restrict__ inds,
                    const float* __restrict__ x,
                    const float* __restrict__ kp,
                    const float* __restrict__ dw,
                    const float* __restrict__ bias,
                    float*       __restrict__ out)
{
    const int wave = threadIdx.x >> 6;
    const int l    = threadIdx.x & 63;
    const int n    = blockIdx.x * 4 + wave;
    const int lg   = l >> 4;
    const int ln   = l & 15;

    const int4* ip = (const int4*)(inds + n * H_NB + lg * 8);
    const int4 i0 = ip[0], i1 = ip[1];
    const int idxv[8] = {i0.x,i0.y,i0.z,i0.w,i1.x,i1.y,i1.z,i1.w};

    const float qx = q_pts[n*3+0], qy = q_pts[n*3+1], qz = q_pts[n*3+2];
    const int kkc = ln < K_KP ? ln : (K_KP - 1);
    const float kpx = kp[kkc*3+0], kpy = kp[kkc*3+1], kpz = kp[kkc*3+2];

    bf16x8 afrag;
#pragma unroll
    for (int j = 0; j < 8; ++j) {
        const int idx = idxv[j];
        const float px = s_pts[idx*3+0] - qx;
        const float py = s_pts[idx*3+1] - qy;
        const float pz = s_pts[idx*3+2] - qz;
        const float dx = px - kpx, dy = py - kpy, dz = pz - kpz;
        const float d  = sqrtf(fmaf(dx, dx, fmaf(dy, dy, dz*dz)));
        float w = fmaxf(1.0f - d * (1.0f/KP_EXT), 0.0f);
        if (ln == 15) w = 0.0f;
        afrag[j] = f2bf(w);
    }

    unsigned boff[8];
#pragma unroll
    for (int j = 0; j < 8; ++j) boff[j] = (unsigned)idxv[j] * C_CH + (unsigned)ln;

    f32x4 acc[8];
#pragma unroll
    for (int t = 0; t < 8; ++t) acc[t] = (f32x4){0.f, 0.f, 0.f, 0.f};
#pragma unroll
    for (int t = 0; t < 8; ++t) {
        bf16x8 bfrag;
#pragma unroll
        for (int j = 0; j < 8; ++j) bfrag[j] = f2bf(x[boff[j] + t*16]);
        acc[t] = __builtin_amdgcn_mfma_f32_16x16x32_bf16(afrag, bfrag, acc[t], 0, 0, 0);
    }

    const int rowbase = lg * 4;
#pragma unroll
    for (int t = 0; t < 8; ++t) {
        const int c = t*16 + ln;
        float s = 0.f;
#pragma unroll
        for (int r = 0; r < 4; ++r) {
            const int row = rowbase + r;
            const float dwv = (row < K_KP) ? dw[row * C_CH + c] : 0.f;
            s = fmaf(dwv, acc[t][r], s);
        }
        s += __shfl_xor(s, 16);
        s += __shfl_xor(s, 32);
        s += bias[c];
        if (l < 16) out[n * C_CH + c] = s;
    }
}

extern "C" void kernel_launch(void* const* d_in, const int* in_sizes, int n_in,
                              void* d_out, int out_size, void* d_ws, size_t ws_size,
                              hipStream_t stream) {
    const float* q_pts = (const float*)d_in[0];
    const float* s_pts = (const float*)d_in[1];
    const int*   inds  = (const int*)  d_in[2];
    const float* x     = (const float*)d_in[3];
    const float* kp    = (const float*)d_in[4];
    const float* dw    = (const float*)d_in[5];
    const float* bias  = (const float*)d_in[6];
    float* out = (float*)d_out;

    const size_t xb_bytes  = (size_t)N_Q * C_CH * sizeof(ushort);   // 12.8 MB
    const size_t sp4_bytes = (size_t)N_Q * sizeof(float4);          // 0.8 MB

    if (ws_size >= xb_bytes + sp4_bytes) {
        ushort* xb  = (ushort*)d_ws;
        float4* sp4 = (float4*)((char*)d_ws + xb_bytes);            // 16B-aligned
        cvt_perm_kernel<<<N_Q / 16, 256, 0, stream>>>(x, s_pts, xb, sp4);
        kpconv_mfma4<<<N_Q / 4, 256, 0, stream>>>(q_pts, sp4, inds, xb,
                                                  kp, dw, bias, out);
    } else {
        kpconv_mfma_fb<<<N_Q / 4, 256, 0, stream>>>(q_pts, s_pts, inds, x,
                                                    kp, dw, bias, out);
    }
}

// Round 9
// 170.338 us; speedup vs baseline: 1.0202x; 1.0202x over previous
//
#include <hip/hip_runtime.h>
#include <hip/hip_bf16.h>

#define N_Q 50000
#define H_NB 32
#define K_KP 15
#define C_CH 128
#define KP_EXT 1.2f

typedef __attribute__((ext_vector_type(8))) short bf16x8;   // MFMA A/B operand
typedef __attribute__((ext_vector_type(4))) float f32x4;    // MFMA C/D

static __device__ __forceinline__ short f2bf(float f) {
    __hip_bfloat16 h = __float2bfloat16(f);   // RNE
    return *reinterpret_cast<short*>(&h);
}

// prepass:
//  (a) xb: x f32 [N,C] -> bf16, channel-permuted c' = (c&15)*8 + (c>>4) so a
//      lane's 8 needed channels (c = t*16+ln) are contiguous;
//  (b) sp4/q4: points as padded float4 (one dwordx4 per gather);
//  (c) kp4: kernel points as float4[16] (k=15 dup-clamped);
//  (d) dwp2: dw permuted so each lane's 4 epilogue rows are one dwordx4:
//      dwp2[(t4*2+half)*64 + lane] = {dw[lg*4+r][half*64+t4*16+ln]}_{r=0..3}
__global__ __launch_bounds__(256)
void prep_kernel(const float* __restrict__ x, const float* __restrict__ s_pts,
                 const float* __restrict__ q_pts, const float* __restrict__ kp,
                 const float* __restrict__ dw,
                 ushort* __restrict__ xb, float4* __restrict__ sp4,
                 float4* __restrict__ q4, float4* __restrict__ kp4,
                 float4* __restrict__ dwp2) {
    const int t  = threadIdx.x;
    const int m  = blockIdx.x * 16 + (t >> 4);   // 3125*16 = 50000 exact
    const int ln = t & 15;
    const float* xr = x + (size_t)m * C_CH;
    uint v[8];
#pragma unroll
    for (int i = 0; i < 8; ++i)
        v[i] = (uint)(ushort)f2bf(xr[ln + 16 * i]);
    uint4 o;
    o.x = v[0] | (v[1] << 16);
    o.y = v[2] | (v[3] << 16);
    o.z = v[4] | (v[5] << 16);
    o.w = v[6] | (v[7] << 16);
    *(uint4*)(xb + (size_t)m * C_CH + ln * 8) = o;
    if (ln == 0)
        sp4[m] = make_float4(s_pts[3*m], s_pts[3*m+1], s_pts[3*m+2], 0.f);
    if (ln == 1)
        q4[m] = make_float4(q_pts[3*m], q_pts[3*m+1], q_pts[3*m+2], 0.f);
    if (blockIdx.x == 0) {
        if (t < 16) {
            const int kk = t < K_KP ? t : (K_KP - 1);
            kp4[t] = make_float4(kp[3*kk], kp[3*kk+1], kp[3*kk+2], 0.f);
        }
        for (int s = t; s < 512; s += 256) {
            const int lane = s & 63, half = (s >> 6) & 1, t4 = s >> 7;
            const int lgg = lane >> 4, lnn = lane & 15;
            const int c = half * 64 + t4 * 16 + lnn;
            float4 w;
            w.x = dw[(lgg*4 + 0) * C_CH + c];
            w.y = dw[(lgg*4 + 1) * C_CH + c];
            w.z = dw[(lgg*4 + 2) * C_CH + c];
            w.w = (lgg*4 + 3 < K_KP) ? dw[(lgg*4 + 3) * C_CH + c] : 0.f;
            dwp2[s] = w;
        }
    }
}

// TWO waves per point (wave half owns column tiles half*4..half*4+3).
// Working set: rv 16 + acc 16 + afrag 4 + offsets ~8 regs -> fits the 64-reg
// total budget -> 8 waves/SIMD. P[k,c] = sum_h w[h,k] x[idx_h,c] via 4x
// mfma_f32_16x16x32_bf16 per wave; A computed per-lane (duplicated per pair).
__global__ __launch_bounds__(256, 8)
void kpconv_mfma5(const float4* __restrict__ q4,
                  const float4* __restrict__ sp4,
                  const int*    __restrict__ inds,
                  const ushort* __restrict__ xb,
                  const float4* __restrict__ kp4,
                  const float4* __restrict__ dwp2,
                  const float*  __restrict__ bias,
                  float*        __restrict__ out)
{
    const int wave = threadIdx.x >> 6;
    const int l    = threadIdx.x & 63;
    const int n    = blockIdx.x * 2 + (wave >> 1);  // 25000*2 = 50000 exact
    const int half = wave & 1;
    const int lg   = l >> 4;
    const int ln   = l & 15;

    const int4* ip = (const int4*)(inds + n * H_NB + lg * 8);
    const int4 i0 = ip[0], i1 = ip[1];
    const int idxv[8] = {i0.x,i0.y,i0.z,i0.w,i1.x,i1.y,i1.z,i1.w};

    // ---- 8 gathers, 8B each: this wave's 4 tiles' channels per row ----
    uint2 rv[8];
#pragma unroll
    for (int j = 0; j < 8; ++j)
        rv[j] = *(const uint2*)(xb + (size_t)(unsigned)idxv[j] * C_CH + ln * 8 + half * 4);

    // ---- A fragment (w) while gathers are in flight ----
    const float4 qn = q4[n];
    const float4 k4 = kp4[ln];
    const float ox = qn.x + k4.x, oy = qn.y + k4.y, oz = qn.z + k4.z;

    bf16x8 afrag;
#pragma unroll
    for (int j = 0; j < 8; ++j) {
        const float4 p = sp4[(unsigned)idxv[j]];
        const float dx = p.x - ox, dy = p.y - oy, dz = p.z - oz;
        const float d  = sqrtf(fmaf(dx, dx, fmaf(dy, dy, dz*dz)));
        float w = fmaxf(1.0f - d * (1.0f/KP_EXT), 0.0f);
        if (ln == 15) w = 0.0f;                 // pad kernel-point row
        afrag[j] = f2bf(w);
    }

    f32x4 acc[4];
#pragma unroll
    for (int t = 0; t < 4; ++t) acc[t] = (f32x4){0.f, 0.f, 0.f, 0.f};

    const uint* rw = (const uint*)&rv[0];       // rw[j*2 + word]
#pragma unroll
    for (int t = 0; t < 4; ++t) {
        const uint sel = (t & 1) ? 0x07060302u : 0x05040100u;  // halfword t&1
        const int  w   = t >> 1;                               // word in uint2
        union { bf16x8 v; uint u[4]; } bf;
#pragma unroll
        for (int r = 0; r < 4; ++r)
            bf.u[r] = __builtin_amdgcn_perm(rw[(2*r+1)*2 + w], rw[(2*r)*2 + w], sel);
        acc[t] = __builtin_amdgcn_mfma_f32_16x16x32_bf16(afrag, bf.v, acc[t], 0, 0, 0);
    }

    // ---- epilogue: out[c] = sum_k dw[k,c]*P[k,c] + bias[c] ----
    const int cbase = half * 64;
#pragma unroll
    for (int t = 0; t < 4; ++t) {
        const float4 dwd = dwp2[(t*2 + half) * 64 + l];   // 4 rows, one dwordx4
        float s;
        s = dwd.x * acc[t][0];
        s = fmaf(dwd.y, acc[t][1], s);
        s = fmaf(dwd.z, acc[t][2], s);
        s = fmaf(dwd.w, acc[t][3], s);
        s += __shfl_xor(s, 16);                 // reduce the 4 row-groups
        s += __shfl_xor(s, 32);
        s += bias[cbase + t*16 + ln];
        if (l < 16) out[n * C_CH + cbase + t*16 + ln] = s;
    }
}

// fallback (ws too small): R5's fp32-gather kernel, known-good at 117us
__global__ __launch_bounds__(256, 4)
void kpconv_mfma_fb(const float* __restrict__ q_pts,
                    const float* __restrict__ s_pts,
                    const int*   __restrict__ inds,
                    const float* __restrict__ x,
                    const float* __restrict__ kp,
                    const float* __restrict__ dw,
                    const float* __restrict__ bias,
                    float*       __restrict__ out)
{
    const int wave = threadIdx.x >> 6;
    const int l    = threadIdx.x & 63;
    const int n    = blockIdx.x * 4 + wave;
    const int lg   = l >> 4;
    const int ln   = l & 15;

    const int4* ip = (const int4*)(inds + n * H_NB + lg * 8);
    const int4 i0 = ip[0], i1 = ip[1];
    const int idxv[8] = {i0.x,i0.y,i0.z,i0.w,i1.x,i1.y,i1.z,i1.w};

    const float qx = q_pts[n*3+0], qy = q_pts[n*3+1], qz = q_pts[n*3+2];
    const int kkc = ln < K_KP ? ln : (K_KP - 1);
    const float kpx = kp[kkc*3+0], kpy = kp[kkc*3+1], kpz = kp[kkc*3+2];

    bf16x8 afrag;
#pragma unroll
    for (int j = 0; j < 8; ++j) {
        const int idx = idxv[j];
        const float px = s_pts[idx*3+0] - qx;
        const float py = s_pts[idx*3+1] - qy;
        const float pz = s_pts[idx*3+2] - qz;
        const float dx = px - kpx, dy = py - kpy, dz = pz - kpz;
        const float d  = sqrtf(fmaf(dx, dx, fmaf(dy, dy, dz*dz)));
        float w = fmaxf(1.0f - d * (1.0f/KP_EXT), 0.0f);
        if (ln == 15) w = 0.0f;
        afrag[j] = f2bf(w);
    }

    unsigned boff[8];
#pragma unroll
    for (int j = 0; j < 8; ++j) boff[j] = (unsigned)idxv[j] * C_CH + (unsigned)ln;

    f32x4 acc[8];
#pragma unroll
    for (int t = 0; t < 8; ++t) acc[t] = (f32x4){0.f, 0.f, 0.f, 0.f};
#pragma unroll
    for (int t = 0; t < 8; ++t) {
        bf16x8 bfrag;
#pragma unroll
        for (int j = 0; j < 8; ++j) bfrag[j] = f2bf(x[boff[j] + t*16]);
        acc[t] = __builtin_amdgcn_mfma_f32_16x16x32_bf16(afrag, bfrag, acc[t], 0, 0, 0);
    }

    const int rowbase = lg * 4;
#pragma unroll
    for (int t = 0; t < 8; ++t) {
        const int c = t*16 + ln;
        float s = 0.f;
#pragma unroll
        for (int r = 0; r < 4; ++r) {
            const int row = rowbase + r;
            const float dwv = (row < K_KP) ? dw[row * C_CH + c] : 0.f;
            s = fmaf(dwv, acc[t][r], s);
        }
        s += __shfl_xor(s, 16);
        s += __shfl_xor(s, 32);
        s += bias[c];
        if (l < 16) out[n * C_CH + c] = s;
    }
}

extern "C" void kernel_launch(void* const* d_in, const int* in_sizes, int n_in,
                              void* d_out, int out_size, void* d_ws, size_t ws_size,
                              hipStream_t stream) {
    const float* q_pts = (const float*)d_in[0];
    const float* s_pts = (const float*)d_in[1];
    const int*   inds  = (const int*)  d_in[2];
    const float* x     = (const float*)d_in[3];
    const float* kp    = (const float*)d_in[4];
    const float* dw    = (const float*)d_in[5];
    const float* bias  = (const float*)d_in[6];
    float* out = (float*)d_out;

    const size_t xb_b   = (size_t)N_Q * C_CH * sizeof(ushort);   // 12.8 MB
    const size_t sp4_b  = (size_t)N_Q * sizeof(float4);          // 0.8 MB
    const size_t q4_b   = (size_t)N_Q * sizeof(float4);          // 0.8 MB
    const size_t kp4_b  = 16 * sizeof(float4);
    const size_t dwp2_b = 512 * sizeof(float4);

    if (ws_size >= xb_b + sp4_b + q4_b + kp4_b + dwp2_b) {
        char* p = (char*)d_ws;
        ushort* xb   = (ushort*)p;                 p += xb_b;
        float4* sp4  = (float4*)p;                 p += sp4_b;
        float4* q4   = (float4*)p;                 p += q4_b;
        float4* kp4  = (float4*)p;                 p += kp4_b;
        float4* dwp2 = (float4*)p;
        prep_kernel<<<N_Q / 16, 256, 0, stream>>>(x, s_pts, q_pts, kp, dw,
                                                  xb, sp4, q4, kp4, dwp2);
        kpconv_mfma5<<<N_Q / 2, 256, 0, stream>>>(q4, sp4, inds, xb,
                                                  kp4, dwp2, bias, out);
    } else {
        kpconv_mfma_fb<<<N_Q / 4, 256, 0, stream>>>(q_pts, s_pts, inds, x,
                                                    kp, dw, bias, out);
    }
}

// Round 11
// 147.714 us; speedup vs baseline: 1.1765x; 1.1532x over previous
//
#include <hip/hip_runtime.h>
#include <hip/hip_bf16.h>

#define N_Q 50000
#define H_NB 32
#define K_KP 15
#define C_CH 128
#define KP_EXT 1.2f

typedef __attribute__((ext_vector_type(8))) short bf16x8;   // MFMA A/B operand
typedef __attribute__((ext_vector_type(4))) float f32x4;    // MFMA C/D

static __device__ __forceinline__ short f2bf(float f) {
    __hip_bfloat16 h = __float2bfloat16(f);   // RNE (prepass only)
    return *reinterpret_cast<short*>(&h);
}

// prepass:
//  (a) xb: x f32 [N,C] -> bf16, channel-permuted c' = (c&15)*8 + (c>>4) so a
//      lane's 8 needed channels (c = t*16+ln) are one contiguous 16B chunk;
//  (b) sp4/q4: points padded to float4 (one dwordx4 per gather);
//  (c) kp4[16]: kernel points as float4; kp4[15] = 1e6 sentinel so the pad
//      row's w falls out of relu naturally (no per-lane select needed);
//  (d) dwp[t*64+lane] = {dw[lg*4+r][t*16+ln]}_{r=0..3}  (row>=15 -> 0).
__global__ __launch_bounds__(256)
void prep_kernel(const float* __restrict__ x, const float* __restrict__ s_pts,
                 const float* __restrict__ q_pts, const float* __restrict__ kp,
                 const float* __restrict__ dw,
                 ushort* __restrict__ xb, float4* __restrict__ sp4,
                 float4* __restrict__ q4, float4* __restrict__ kp4,
                 float4* __restrict__ dwp) {
    const int t  = threadIdx.x;
    const int m  = blockIdx.x * 16 + (t >> 4);   // 3125*16 = 50000 exact
    const int ln = t & 15;
    const float* xr = x + (size_t)m * C_CH;
    uint v[8];
#pragma unroll
    for (int i = 0; i < 8; ++i)
        v[i] = (uint)(ushort)f2bf(xr[ln + 16 * i]);
    uint4 o;
    o.x = v[0] | (v[1] << 16);
    o.y = v[2] | (v[3] << 16);
    o.z = v[4] | (v[5] << 16);
    o.w = v[6] | (v[7] << 16);
    *(uint4*)(xb + (size_t)m * C_CH + ln * 8) = o;
    if (ln == 0)
        sp4[m] = make_float4(s_pts[3*m], s_pts[3*m+1], s_pts[3*m+2], 0.f);
    if (ln == 1)
        q4[m] = make_float4(q_pts[3*m], q_pts[3*m+1], q_pts[3*m+2], 0.f);
    if (blockIdx.x == 0) {
        if (t < 16) {
            if (t < K_KP) kp4[t] = make_float4(kp[3*t], kp[3*t+1], kp[3*t+2], 0.f);
            else          kp4[t] = make_float4(1e6f, 1e6f, 1e6f, 0.f);   // sentinel
        }
        for (int s = t; s < 512; s += 256) {
            const int lane = s & 63, tt = s >> 6;
            const int lgg = lane >> 4, lnn = lane & 15;
            const int c = tt * 16 + lnn;
            float4 w;
            w.x = dw[(lgg*4 + 0) * C_CH + c];
            w.y = dw[(lgg*4 + 1) * C_CH + c];
            w.z = dw[(lgg*4 + 2) * C_CH + c];
            w.w = (lgg*4 + 3 < K_KP) ? dw[(lgg*4 + 3) * C_CH + c] : 0.f;
            dwp[s] = w;
        }
    }
}

// One wave per point, register-only. P[k,c] = sum_h w[h,k] x[idx_h,c] via
// 8x mfma_f32_16x16x32_bf16; A (w) computed per-lane directly in fragment
// layout (fast sqrt, truncation-pack to bf16); B from 8 fat 16B gathers of
// the permuted xb, redistributed with compile-time v_perm_b32.
__global__ __launch_bounds__(256, 4)
void kpconv_mfma6(const float4* __restrict__ q4,
                  const float4* __restrict__ sp4,
                  const int*    __restrict__ inds,
                  const ushort* __restrict__ xb,
                  const float4* __restrict__ kp4,
                  const float4* __restrict__ dwp,
                  const float*  __restrict__ bias,
                  float*        __restrict__ out)
{
    const int wave = threadIdx.x >> 6;
    const int l    = threadIdx.x & 63;
    const int n    = blockIdx.x * 4 + wave;     // 12500*4 = 50000 exact
    const int lg   = l >> 4;                    // h-block 0..3
    const int ln   = l & 15;                    // k (A) / col (B,C)

    const int4* ip = (const int4*)(inds + n * H_NB + lg * 8);
    const int4 i0 = ip[0], i1 = ip[1];
    const int idxv[8] = {i0.x,i0.y,i0.z,i0.w,i1.x,i1.y,i1.z,i1.w};

    // ---- 8 fat x-gathers, 32-bit byte offsets (saddr+voffset form) ----
    uint4 rv[8];
#pragma unroll
    for (int j = 0; j < 8; ++j)
        rv[j] = *(const uint4*)((const char*)xb +
                    ((unsigned)idxv[j] * 256u + (unsigned)(ln * 16)));

    // ---- neighbor coords (32-bit offsets), then w while gathers fly ----
    float4 pj[8];
#pragma unroll
    for (int j = 0; j < 8; ++j)
        pj[j] = *(const float4*)((const char*)sp4 + (unsigned)idxv[j] * 16u);

    const float4 qn = q4[n];
    const float4 k4 = kp4[ln];                  // ln==15 -> 1e6 sentinel
    const float ox = qn.x + k4.x, oy = qn.y + k4.y, oz = qn.z + k4.z;

    float wv[8];
#pragma unroll
    for (int j = 0; j < 8; ++j) {
        const float dx = pj[j].x - ox, dy = pj[j].y - oy, dz = pj[j].z - oz;
        const float sq = fmaf(dx, dx, fmaf(dy, dy, dz*dz));
        const float d  = __builtin_amdgcn_sqrtf(sq);      // raw v_sqrt_f32
        wv[j] = fmaxf(1.0f - d * (1.0f/KP_EXT), 0.0f);
    }

    // truncation-pack: one v_perm per bf16 pair (even in lo16, odd in hi16)
    union { bf16x8 v; uint u[4]; } af;
#pragma unroll
    for (int jj = 0; jj < 4; ++jj)
        af.u[jj] = __builtin_amdgcn_perm(__float_as_uint(wv[2*jj+1]),
                                         __float_as_uint(wv[2*jj]),
                                         0x07060302u);

    f32x4 acc[8];
#pragma unroll
    for (int t = 0; t < 8; ++t) acc[t] = (f32x4){0.f, 0.f, 0.f, 0.f};

    const uint* rw = (const uint*)&rv[0];       // rw[j*4 + word], const idx
#pragma unroll
    for (int t = 0; t < 8; ++t) {
        const uint sel = (t & 1) ? 0x07060302u : 0x05040100u;  // halfword t&1
        const int  w   = t >> 1;                               // word in uint4
        union { bf16x8 v; uint u[4]; } bf;
#pragma unroll
        for (int r = 0; r < 4; ++r)
            bf.u[r] = __builtin_amdgcn_perm(rw[(2*r+1)*4 + w], rw[(2*r)*4 + w], sel);
        acc[t] = __builtin_amdgcn_mfma_f32_16x16x32_bf16(af.v, bf.v, acc[t], 0, 0, 0);
    }

    // ---- epilogue: out[c] = sum_k dw[k,c]*P[k,c] + bias[c] ----
    float sfin[8];
#pragma unroll
    for (int t = 0; t < 8; ++t) {
        const float4 dwd = dwp[t*64 + l];       // 4 rows in one dwordx4
        float sv;
        sv = dwd.x * acc[t][0];
        sv = fmaf(dwd.y, acc[t][1], sv);
        sv = fmaf(dwd.z, acc[t][2], sv);
        sv = fmaf(dwd.w, acc[t][3], sv);
        sv += __shfl_xor(sv, 16);               // full butterfly: every lane
        sv += __shfl_xor(sv, 32);               // ends with the total
        sfin[t] = sv + bias[t*16 + ln];
    }

    // lane (lg,ln) stores tiles 2lg and 2lg+1 (c = lg*32 + {0,16} + ln):
    // compile-time-indexed cndmask ladder, all 64 lanes store (no exec mask)
    const float a0 = (lg & 1) ? sfin[2] : sfin[0];
    const float a1 = (lg & 1) ? sfin[3] : sfin[1];
    const float b0 = (lg & 1) ? sfin[6] : sfin[4];
    const float b1 = (lg & 1) ? sfin[7] : sfin[5];
    const float o0 = (lg & 2) ? b0 : a0;
    const float o1 = (lg & 2) ? b1 : a1;
    float* op = out + n * C_CH + lg * 32 + ln;
    op[0]  = o0;
    op[16] = o1;
}

// fallback (ws too small): R5's fp32-gather kernel, known-good at 117us
__global__ __launch_bounds__(256, 4)
void kpconv_mfma_fb(const float* __restrict__ q_pts,
                    const float* __restrict__ s_pts,
                    const int*   __restrict__ inds,
                    const float* __restrict__ x,
                    const float* __restrict__ kp,
                    const float* __restrict__ dw,
                    const float* __restrict__ bias,
                    float*       __restrict__ out)
{
    const int wave = threadIdx.x >> 6;
    const int l    = threadIdx.x & 63;
    const int n    = blockIdx.x * 4 + wave;
    const int lg   = l >> 4;
    const int ln   = l & 15;

    const int4* ip = (const int4*)(inds + n * H_NB + lg * 8);
    const int4 i0 = ip[0], i1 = ip[1];
    const int idxv[8] = {i0.x,i0.y,i0.z,i0.w,i1.x,i1.y,i1.z,i1.w};

    const float qx = q_pts[n*3+0], qy = q_pts[n*3+1], qz = q_pts[n*3+2];
    const int kkc = ln < K_KP ? ln : (K_KP - 1);
    const float kpx = kp[kkc*3+0], kpy = kp[kkc*3+1], kpz = kp[kkc*3+2];

    bf16x8 afrag;
#pragma unroll
    for (int j = 0; j < 8; ++j) {
        const int idx = idxv[j];
        const float px = s_pts[idx*3+0] - qx;
        const float py = s_pts[idx*3+1] - qy;
        const float pz = s_pts[idx*3+2] - qz;
        const float dx = px - kpx, dy = py - kpy, dz = pz - kpz;
        const float d  = sqrtf(fmaf(dx, dx, fmaf(dy, dy, dz*dz)));
        float w = fmaxf(1.0f - d * (1.0f/KP_EXT), 0.0f);
        if (ln == 15) w = 0.0f;
        afrag[j] = f2bf(w);
    }

    unsigned boff[8];
#pragma unroll
    for (int j = 0; j < 8; ++j) boff[j] = (unsigned)idxv[j] * C_CH + (unsigned)ln;

    f32x4 acc[8];
#pragma unroll
    for (int t = 0; t < 8; ++t) acc[t] = (f32x4){0.f, 0.f, 0.f, 0.f};
#pragma unroll
    for (int t = 0; t < 8; ++t) {
        bf16x8 bfrag;
#pragma unroll
        for (int j = 0; j < 8; ++j) bfrag[j] = f2bf(x[boff[j] + t*16]);
        acc[t] = __builtin_amdgcn_mfma_f32_16x16x32_bf16(afrag, bfrag, acc[t], 0, 0, 0);
    }

    const int rowbase = lg * 4;
#pragma unroll
    for (int t = 0; t < 8; ++t) {
        const int c = t*16 + ln;
        float s = 0.f;
#pragma unroll
        for (int r = 0; r < 4; ++r) {
            const int row = rowbase + r;
            const float dwv = (row < K_KP) ? dw[row * C_CH + c] : 0.f;
            s = fmaf(dwv, acc[t][r], s);
        }
        s += __shfl_xor(s, 16);
        s += __shfl_xor(s, 32);
        s += bias[c];
        if (l < 16) out[n * C_CH + c] = s;
    }
}

extern "C" void kernel_launch(void* const* d_in, const int* in_sizes, int n_in,
                              void* d_out, int out_size, void* d_ws, size_t ws_size,
                              hipStream_t stream) {
    const float* q_pts = (const float*)d_in[0];
    const float* s_pts = (const float*)d_in[1];
    const int*   inds  = (const int*)  d_in[2];
    const float* x     = (const float*)d_in[3];
    const float* kp    = (const float*)d_in[4];
    const float* dw    = (const float*)d_in[5];
    const float* bias  = (const float*)d_in[6];
    float* out = (float*)d_out;

    const size_t xb_b  = (size_t)N_Q * C_CH * sizeof(ushort);   // 12.8 MB
    const size_t sp4_b = (size_t)N_Q * sizeof(float4);          // 0.8 MB
    const size_t q4_b  = (size_t)N_Q * sizeof(float4);          // 0.8 MB
    const size_t kp4_b = 16 * sizeof(float4);
    const size_t dwp_b = 512 * sizeof(float4);

    if (ws_size >= xb_b + sp4_b + q4_b + kp4_b + dwp_b) {
        char* p = (char*)d_ws;
        ushort* xb  = (ushort*)p;  p += xb_b;
        float4* sp4 = (float4*)p;  p += sp4_b;
        float4* q4  = (float4*)p;  p += q4_b;
        float4* kp4 = (float4*)p;  p += kp4_b;
        float4* dwp = (float4*)p;
        prep_kernel<<<N_Q / 16, 256, 0, stream>>>(x, s_pts, q_pts, kp, dw,
                                                  xb, sp4, q4, kp4, dwp);
        kpconv_mfma6<<<N_Q / 4, 256, 0, stream>>>(q4, sp4, inds, xb,
                                                  kp4, dwp, bias, out);
    } else {
        kpconv_mfma_fb<<<N_Q / 4, 256, 0, stream>>>(q_pts, s_pts, inds, x,
                                                    kp, dw, bias, out);
    }
}